// Round 4
// baseline (966.520 us; speedup 1.0000x reference)
//
#include <hip/hip_runtime.h>
#include <hip/hip_bf16.h>
#include <stdint.h>
#include <stddef.h>

typedef unsigned short u16;
typedef short bf16x8 __attribute__((ext_vector_type(8)));   // 8 bf16 = 4 VGPRs
typedef short bf16x4 __attribute__((ext_vector_type(4)));   // 4 bf16 = 2 VGPRs
typedef float floatx4 __attribute__((ext_vector_type(4)));

#define N_ROWS 8192
#define D_MODEL 1024
#define PROJ 512
#define GSPLIT 4
#define KEYS_PER_G (N_ROWS / GSPLIT)   // 2048
#define CHUNKS (KEYS_PER_G / 32)       // 64
// exp(S/64) = 2^(S * log2(e)/64)
#define SCALE_LOG2E_DK 0.022542110013890054f

__device__ __forceinline__ u16 f2bf(float f) {
    __hip_bfloat16 h = __float2bfloat16(f);   // RNE
    return *reinterpret_cast<u16*>(&h);
}

// ------------------------------------------------- W transpose fp32 -> bf16
// in fp32 [R][C] -> out bf16 [C][R]
__global__ void transpose_w_kernel(const float* __restrict__ in, u16* __restrict__ out,
                                   int R, int C) {
    __shared__ u16 tile[32][33];
    int r = blockIdx.y * 32 + threadIdx.y;
    int c = blockIdx.x * 32 + threadIdx.x;
    tile[threadIdx.y][threadIdx.x] = f2bf(in[(size_t)r * C + c]);
    __syncthreads();
    int ro = blockIdx.x * 32 + threadIdx.y;
    int co = blockIdx.y * 32 + threadIdx.x;
    out[(size_t)ro * R + co] = tile[threadIdx.x][threadIdx.y];
}

// ------------------------------------------------- bf16 transpose (vp->vpT)
__global__ void transpose_kernel(const u16* __restrict__ in, u16* __restrict__ out,
                                 int R, int C) {
    __shared__ u16 tile[32][33];
    int r = blockIdx.y * 32 + threadIdx.y;
    int c = blockIdx.x * 32 + threadIdx.x;
    tile[threadIdx.y][threadIdx.x] = in[(size_t)r * C + c];
    __syncthreads();
    int ro = blockIdx.x * 32 + threadIdx.y;
    int co = blockIdx.y * 32 + threadIdx.x;
    out[(size_t)ro * R + co] = tile[threadIdx.x][threadIdx.y];
}

// ---------------------------------------------------------------- projections
// C_bf16[8192,512] = A_f32[8192,1024] @ W[1024,512] + b, via WT_bf16[512,1024].
// 128x128 tile, BK=32, 4 waves each 64x64 (4x4 of 16x16x32 MFMA).
// A staged fp32->bf16 in flight; padded LDS stride 40 u16.  LDS: 20,480 B.
__global__ __launch_bounds__(256) void proj_kernel(
    const float* __restrict__ qin, const float* __restrict__ kin, const float* __restrict__ vin,
    const u16* __restrict__ WqT, const u16* __restrict__ WkT, const u16* __restrict__ WvT,
    const float* __restrict__ bq, const float* __restrict__ bk, const float* __restrict__ bv,
    u16* __restrict__ qp, u16* __restrict__ kp, u16* __restrict__ vp)
{
    const int z = blockIdx.z;
    const float* A    = (z == 0) ? qin : (z == 1) ? kin : vin;
    const u16* WT     = (z == 0) ? WqT : (z == 1) ? WkT : WvT;
    const float* bias = (z == 0) ? bq  : (z == 1) ? bk  : bv;
    u16* C            = (z == 0) ? qp  : (z == 1) ? kp  : vp;

    const int m0 = blockIdx.x * 128;
    const int n0 = blockIdx.y * 128;
    __shared__ __align__(16) u16 smem[2 * 128 * 40];   // 20,480 B
    u16* As = smem;                // [128 rows][32 + 8 pad] bf16
    u16* Bs = smem + 128 * 40;

    const int t = threadIdx.x;
    const int w = t >> 6, l = t & 63;
    const int q16 = l >> 4, l16 = l & 15;
    const int wm = (w & 1) * 64, wn = (w >> 1) * 64;

    floatx4 acc[4][4] = {};

    for (int k0 = 0; k0 < D_MODEL; k0 += 32) {
        __syncthreads();
        // A: 128 rows x 8 float4-chunks -> bf16x4 into LDS (1024 chunks, 4/thread)
#pragma unroll
        for (int i = 0; i < 4; ++i) {
            int id = i * 256 + t;
            int r = id >> 3, c = id & 7;
            float4 f = *(const float4*)(A + (size_t)(m0 + r) * D_MODEL + k0 + c * 4);
            bf16x4 hv;
            hv[0] = (short)f2bf(f.x); hv[1] = (short)f2bf(f.y);
            hv[2] = (short)f2bf(f.z); hv[3] = (short)f2bf(f.w);
            *(bf16x4*)(As + r * 40 + c * 4) = hv;
        }
        // B (already bf16): 128 rows x 4 chunks(16B), 512 chunks, 2/thread
#pragma unroll
        for (int i = 0; i < 2; ++i) {
            int id = i * 256 + t;
            int r = id >> 2, c = id & 3;
            *(bf16x8*)(Bs + r * 40 + c * 8) =
                *(const bf16x8*)(WT + (size_t)(n0 + r) * D_MODEL + k0 + c * 8);
        }
        __syncthreads();

        bf16x8 af[4], bfr[4];
#pragma unroll
        for (int mi = 0; mi < 4; ++mi)
            af[mi] = *(const bf16x8*)(As + (wm + mi * 16 + l16) * 40 + q16 * 8);
#pragma unroll
        for (int ni = 0; ni < 4; ++ni)
            bfr[ni] = *(const bf16x8*)(Bs + (wn + ni * 16 + l16) * 40 + q16 * 8);
#pragma unroll
        for (int mi = 0; mi < 4; ++mi)
#pragma unroll
            for (int ni = 0; ni < 4; ++ni)
                acc[mi][ni] = __builtin_amdgcn_mfma_f32_16x16x32_bf16(
                    af[mi], bfr[ni], acc[mi][ni], 0, 0, 0);
    }

#pragma unroll
    for (int ni = 0; ni < 4; ++ni) {
        int col = n0 + wn + ni * 16 + l16;
        float bv_ = bias[col];
#pragma unroll
        for (int mi = 0; mi < 4; ++mi)
#pragma unroll
            for (int rr = 0; rr < 4; ++rr) {
                int row = m0 + wm + mi * 16 + q16 * 4 + rr;   // C/D layout (m89/m91)
                C[(size_t)row * PROJ + col] = f2bf(acc[mi][ni][rr] + bv_);
            }
    }
}

// ---------------------------------------------------------------- attention
// Flash-lite (scores tiny; clamp guards exp). Block: 64 Q-rows, 4 waves x 16.
// Split-K over keys (GSPLIT groups), BN=32 keys/chunk. qp frags in regs;
// V B-frags direct from global vpT.  LDS: 38,400 B.
__global__ __launch_bounds__(256) void attn_kernel(
    const u16* __restrict__ qp, const u16* __restrict__ kp, const u16* __restrict__ vpT,
    float* __restrict__ O_part, float* __restrict__ l_part)
{
    const int t = threadIdx.x;
    const int w = t >> 6, l = t & 63;
    const int q16 = l >> 4, l16 = l & 15;
    const int qt = blockIdx.x, g = blockIdx.y;
    const int q0 = qt * 64 + w * 16;

    __shared__ __align__(16) u16 KPs[32 * 520];    // [32 keys][512 + 8 pad]
    __shared__ __align__(16) u16 PsA[4 * 16 * 40]; // per-wave P 16x(32+8)
    u16* Ps = PsA + w * 640;

    bf16x8 qf[16];
#pragma unroll
    for (int s = 0; s < 16; ++s)
        qf[s] = *(const bf16x8*)(qp + (size_t)(q0 + l16) * PROJ + s * 32 + q16 * 8);

    floatx4 acc[32] = {};
    float lsum[4] = {0.f, 0.f, 0.f, 0.f};
    const int kbase = g * KEYS_PER_G;
    const u16* vbase = vpT + (size_t)l16 * N_ROWS + q16 * 8;

    for (int ci = 0; ci < CHUNKS; ++ci) {
        const int k0 = kbase + ci * 32;
        __syncthreads();
#pragma unroll
        for (int i = 0; i < 8; ++i) {
            int id = i * 256 + t;
            int r = id >> 6, c = id & 63;
            *(bf16x8*)(KPs + r * 520 + c * 8) =
                *(const bf16x8*)(kp + (size_t)(k0 + r) * PROJ + c * 8);
        }
        __syncthreads();

        floatx4 S[2] = {};
#pragma unroll
        for (int nt = 0; nt < 2; ++nt) {
            const u16* rowp = KPs + (nt * 16 + l16) * 520;
#pragma unroll
            for (int s = 0; s < 16; ++s) {
                bf16x8 b = *(const bf16x8*)(rowp + s * 32 + q16 * 8);
                S[nt] = __builtin_amdgcn_mfma_f32_16x16x32_bf16(qf[s], b, S[nt], 0, 0, 0);
            }
        }
#pragma unroll
        for (int nt = 0; nt < 2; ++nt)
#pragma unroll
            for (int rr = 0; rr < 4; ++rr) {
                float x = S[nt][rr] * SCALE_LOG2E_DK;
                x = fminf(fmaxf(x, -30.f), 30.f);
                float p = exp2f(x);
                lsum[rr] += p;
                Ps[(q16 * 4 + rr) * 40 + nt * 16 + l16] = f2bf(p);
            }
        bf16x8 pf = *(const bf16x8*)(Ps + l16 * 40 + q16 * 8);
        const u16* vp0 = vbase + k0;
#pragma unroll
        for (int nt = 0; nt < 32; ++nt) {
            bf16x8 b = *(const bf16x8*)(vp0 + (size_t)nt * 16 * N_ROWS);
            acc[nt] = __builtin_amdgcn_mfma_f32_16x16x32_bf16(pf, b, acc[nt], 0, 0, 0);
        }
    }

#pragma unroll
    for (int m = 1; m < 16; m <<= 1)
#pragma unroll
        for (int rr = 0; rr < 4; ++rr)
            lsum[rr] += __shfl_xor(lsum[rr], m, 64);

    if (l16 == 0) {
#pragma unroll
        for (int rr = 0; rr < 4; ++rr)
            l_part[g * N_ROWS + q0 + q16 * 4 + rr] = lsum[rr];
    }
    float* Ob = O_part + ((size_t)g * N_ROWS + q0) * PROJ;
#pragma unroll
    for (int nt = 0; nt < 32; ++nt)
#pragma unroll
        for (int rr = 0; rr < 4; ++rr)
            Ob[(size_t)(q16 * 4 + rr) * PROJ + nt * 16 + l16] = acc[nt][rr];
}

// ---------------------------------------------------------------- combine
__global__ void combine_kernel(const float* __restrict__ O_part,
                               const float* __restrict__ l_part,
                               float* __restrict__ out)
{
    int idx = blockIdx.x * 256 + threadIdx.x;   // 8192*128
    int row = idx >> 7;
    int c4 = (idx & 127) << 2;
    float s0 = 0, s1 = 0, s2 = 0, s3 = 0, lt = 0;
#pragma unroll
    for (int g = 0; g < GSPLIT; ++g) {
        const float* p = O_part + ((size_t)g * N_ROWS + row) * PROJ + c4;
        s0 += p[0]; s1 += p[1]; s2 += p[2]; s3 += p[3];
        lt += l_part[g * N_ROWS + row];
    }
    size_t o = (size_t)row * PROJ + c4;
    if (!(lt > 0.f)) {   // attn never wrote l_part -> finite signature 2.0
        out[o + 0] = 2.0f; out[o + 1] = 2.0f; out[o + 2] = 2.0f; out[o + 3] = 2.0f;
        return;
    }
    float inv = 1.0f / lt;
    out[o + 0] = s0 * inv;
    out[o + 1] = s1 * inv;
    out[o + 2] = s2 * inv;
    out[o + 3] = s3 * inv;
}

// ---------------------------------------------------------------- launch
extern "C" void kernel_launch(void* const* d_in, const int* in_sizes, int n_in,
                              void* d_out, int out_size, void* d_ws, size_t ws_size,
                              hipStream_t stream)
{
    (void)in_sizes; (void)n_in; (void)out_size;
    if (ws_size < ((size_t)101 << 20)) return;   // visible-fail guard

    const float* q  = (const float*)d_in[0];
    const float* k  = (const float*)d_in[1];
    const float* v  = (const float*)d_in[2];
    const float* Wq = (const float*)d_in[3];
    const float* bq = (const float*)d_in[4];
    const float* Wk = (const float*)d_in[5];
    const float* bk = (const float*)d_in[6];
    const float* Wv = (const float*)d_in[7];
    const float* bv = (const float*)d_in[8];

    char* ws = (char*)d_ws;
    u16* qp  = (u16*)(ws);                         // 8 MB
    u16* kp  = (u16*)(ws + ((size_t)8  << 20));    // 8 MB
    u16* vp  = (u16*)(ws + ((size_t)16 << 20));    // 8 MB
    u16* vpT = (u16*)(ws + ((size_t)24 << 20));    // 8 MB
    u16* WqT = (u16*)(ws + ((size_t)32 << 20));    // 1 MB each (bf16 512x1024)
    u16* WkT = (u16*)(ws + ((size_t)33 << 20));
    u16* WvT = (u16*)(ws + ((size_t)34 << 20));
    float* O_part = (float*)(ws + ((size_t)36 << 20));   // 64 MB
    float* l_part = (float*)(ws + ((size_t)100 << 20));  // 128 KB

    dim3 tb(32, 32);
    transpose_w_kernel<<<dim3(16, 32), tb, 0, stream>>>(Wq, WqT, 1024, 512);
    transpose_w_kernel<<<dim3(16, 32), tb, 0, stream>>>(Wk, WkT, 1024, 512);
    transpose_w_kernel<<<dim3(16, 32), tb, 0, stream>>>(Wv, WvT, 1024, 512);

    proj_kernel<<<dim3(64, 4, 3), 256, 0, stream>>>(q, k, v, WqT, WkT, WvT,
                                                    bq, bk, bv, qp, kp, vp);

    transpose_kernel<<<dim3(16, 256), tb, 0, stream>>>(vp, vpT, 8192, 512);

    attn_kernel<<<dim3(128, GSPLIT), 256, 0, stream>>>(qp, kp, vpT, O_part, l_part);

    combine_kernel<<<4096, 256, 0, stream>>>(O_part, l_part, (float*)d_out);
}

// Round 5
// 919.713 us; speedup vs baseline: 1.0509x; 1.0509x over previous
//
#include <hip/hip_runtime.h>
#include <hip/hip_bf16.h>
#include <stdint.h>
#include <stddef.h>

typedef unsigned short u16;
typedef short bf16x8 __attribute__((ext_vector_type(8)));   // 8 bf16 = 4 VGPRs
typedef short bf16x4 __attribute__((ext_vector_type(4)));   // 4 bf16 = 2 VGPRs
typedef float floatx4 __attribute__((ext_vector_type(4)));

#define N_ROWS 8192
#define D_MODEL 1024
#define PROJ 512
#define GSPLIT 4
#define KEYS_PER_G (N_ROWS / GSPLIT)   // 2048
#define CHUNKS (KEYS_PER_G / 32)       // 64
// exp(S/64) = 2^(S * log2(e)/64)
#define SCALE_LOG2E_DK 0.022542110013890054f

__device__ __forceinline__ u16 f2bf(float f) {
    __hip_bfloat16 h = __float2bfloat16(f);   // RNE
    return *reinterpret_cast<u16*>(&h);
}

// ------------------------------------------------- W transpose fp32 -> bf16
__global__ void transpose_w_kernel(const float* __restrict__ in, u16* __restrict__ out,
                                   int R, int C) {
    __shared__ u16 tile[32][33];
    int r = blockIdx.y * 32 + threadIdx.y;
    int c = blockIdx.x * 32 + threadIdx.x;
    tile[threadIdx.y][threadIdx.x] = f2bf(in[(size_t)r * C + c]);
    __syncthreads();
    int ro = blockIdx.x * 32 + threadIdx.y;
    int co = blockIdx.y * 32 + threadIdx.x;
    out[(size_t)ro * R + co] = tile[threadIdx.x][threadIdx.y];
}

// ------------------------------------------------- bf16 transpose (vp->vpT)
__global__ void transpose_kernel(const u16* __restrict__ in, u16* __restrict__ out,
                                 int R, int C) {
    __shared__ u16 tile[32][33];
    int r = blockIdx.y * 32 + threadIdx.y;
    int c = blockIdx.x * 32 + threadIdx.x;
    tile[threadIdx.y][threadIdx.x] = in[(size_t)r * C + c];
    __syncthreads();
    int ro = blockIdx.x * 32 + threadIdx.y;
    int co = blockIdx.y * 32 + threadIdx.x;
    out[(size_t)ro * R + co] = tile[threadIdx.x][threadIdx.y];
}

// ---------------------------------------------------------------- projections
// C_bf16[8192,512] = A_f32[8192,1024] @ W[1024,512] + b, via WT_bf16[512,1024].
// 128x128 tile, BK=32, 4 waves each 64x64 (4x4 of 16x16x32 MFMA).
__global__ __launch_bounds__(256) void proj_kernel(
    const float* __restrict__ qin, const float* __restrict__ kin, const float* __restrict__ vin,
    const u16* __restrict__ WqT, const u16* __restrict__ WkT, const u16* __restrict__ WvT,
    const float* __restrict__ bq, const float* __restrict__ bk, const float* __restrict__ bv,
    u16* __restrict__ qp, u16* __restrict__ kp, u16* __restrict__ vp)
{
    const int z = blockIdx.z;
    const float* A    = (z == 0) ? qin : (z == 1) ? kin : vin;
    const u16* WT     = (z == 0) ? WqT : (z == 1) ? WkT : WvT;
    const float* bias = (z == 0) ? bq  : (z == 1) ? bk  : bv;
    u16* C            = (z == 0) ? qp  : (z == 1) ? kp  : vp;

    const int m0 = blockIdx.x * 128;
    const int n0 = blockIdx.y * 128;
    __shared__ __align__(16) u16 smem[2 * 128 * 40];   // 20,480 B
    u16* As = smem;                // [128 rows][32 + 8 pad] bf16
    u16* Bs = smem + 128 * 40;

    const int t = threadIdx.x;
    const int w = t >> 6, l = t & 63;
    const int q16 = l >> 4, l16 = l & 15;
    const int wm = (w & 1) * 64, wn = (w >> 1) * 64;

    floatx4 acc[4][4] = {};

    for (int k0 = 0; k0 < D_MODEL; k0 += 32) {
        __syncthreads();
#pragma unroll
        for (int i = 0; i < 4; ++i) {
            int id = i * 256 + t;
            int r = id >> 3, c = id & 7;
            float4 f = *(const float4*)(A + (size_t)(m0 + r) * D_MODEL + k0 + c * 4);
            bf16x4 hv;
            hv[0] = (short)f2bf(f.x); hv[1] = (short)f2bf(f.y);
            hv[2] = (short)f2bf(f.z); hv[3] = (short)f2bf(f.w);
            *(bf16x4*)(As + r * 40 + c * 4) = hv;
        }
#pragma unroll
        for (int i = 0; i < 2; ++i) {
            int id = i * 256 + t;
            int r = id >> 2, c = id & 3;
            *(bf16x8*)(Bs + r * 40 + c * 8) =
                *(const bf16x8*)(WT + (size_t)(n0 + r) * D_MODEL + k0 + c * 8);
        }
        __syncthreads();

        bf16x8 af[4], bfr[4];
#pragma unroll
        for (int mi = 0; mi < 4; ++mi)
            af[mi] = *(const bf16x8*)(As + (wm + mi * 16 + l16) * 40 + q16 * 8);
#pragma unroll
        for (int ni = 0; ni < 4; ++ni)
            bfr[ni] = *(const bf16x8*)(Bs + (wn + ni * 16 + l16) * 40 + q16 * 8);
#pragma unroll
        for (int mi = 0; mi < 4; ++mi)
#pragma unroll
            for (int ni = 0; ni < 4; ++ni)
                acc[mi][ni] = __builtin_amdgcn_mfma_f32_16x16x32_bf16(
                    af[mi], bfr[ni], acc[mi][ni], 0, 0, 0);
    }

#pragma unroll
    for (int ni = 0; ni < 4; ++ni) {
        int col = n0 + wn + ni * 16 + l16;
        float bv_ = bias[col];
#pragma unroll
        for (int mi = 0; mi < 4; ++mi)
#pragma unroll
            for (int rr = 0; rr < 4; ++rr) {
                int row = m0 + wm + mi * 16 + q16 * 4 + rr;   // C/D layout (m89/m91)
                C[(size_t)row * PROJ + col] = f2bf(acc[mi][ni][rr] + bv_);
            }
    }
}

// ---------------------------------------------------------------- attention
// Flash-lite. Block: 64 Q-rows, 4 waves x 16 rows. Split-K (GSPLIT), BN=32.
// Round-5: V chunk staged in LDS (kills 4x-redundant global V reads that made
// R4 latency-bound: MfmaUtil 7%, all pipes idle).  LDS: 79,360 B (2 blocks/CU).
__global__ __launch_bounds__(256) void attn_kernel(
    const u16* __restrict__ qp, const u16* __restrict__ kp, const u16* __restrict__ vpT,
    float* __restrict__ O_part, float* __restrict__ l_part)
{
    const int t = threadIdx.x;
    const int w = t >> 6, l = t & 63;
    const int q16 = l >> 4, l16 = l & 15;
    const int qt = blockIdx.x, g = blockIdx.y;
    const int q0 = qt * 64 + w * 16;

    __shared__ __align__(16) u16 KPs[32 * 520];    // [32 keys][512 + 8 pad]  33,280 B
    __shared__ __align__(16) u16 VPs[512 * 40];    // [512 n][32 + 8 pad]     40,960 B
    __shared__ __align__(16) u16 PsA[4 * 16 * 40]; // per-wave P 16x(32+8)     5,120 B
    u16* Ps = PsA + w * 640;

    bf16x8 qf[16];
#pragma unroll
    for (int s = 0; s < 16; ++s)
        qf[s] = *(const bf16x8*)(qp + (size_t)(q0 + l16) * PROJ + s * 32 + q16 * 8);

    floatx4 acc[32] = {};
    float lsum[4] = {0.f, 0.f, 0.f, 0.f};
    const int kbase = g * KEYS_PER_G;

    for (int ci = 0; ci < CHUNKS; ++ci) {
        const int k0 = kbase + ci * 32;
        __syncthreads();
        // stage KP chunk: 32 rows x 64 chunks(16B); per wave: 1KB-contig rows
#pragma unroll
        for (int i = 0; i < 8; ++i) {
            int id = i * 256 + t;
            int r = id >> 6, c = id & 63;
            *(bf16x8*)(KPs + r * 520 + c * 8) =
                *(const bf16x8*)(kp + (size_t)(k0 + r) * PROJ + c * 8);
        }
        // stage VP chunk: 512 rows x 4 chunks(16B) from vpT[n][k]
#pragma unroll
        for (int i = 0; i < 8; ++i) {
            int id = i * 256 + t;
            int n = id >> 2, c = id & 3;
            *(bf16x8*)(VPs + n * 40 + c * 8) =
                *(const bf16x8*)(vpT + (size_t)n * N_ROWS + k0 + c * 8);
        }
        __syncthreads();

        // S[16x32] = qp_tile @ kp_chunk^T
        floatx4 S[2] = {};
#pragma unroll
        for (int nt = 0; nt < 2; ++nt) {
            const u16* rowp = KPs + (nt * 16 + l16) * 520;
#pragma unroll
            for (int s = 0; s < 16; ++s) {
                bf16x8 b = *(const bf16x8*)(rowp + s * 32 + q16 * 8);
                S[nt] = __builtin_amdgcn_mfma_f32_16x16x32_bf16(qf[s], b, S[nt], 0, 0, 0);
            }
        }
        // P = exp2(clamp(S*c)); row-sum partials; C-layout -> LDS
#pragma unroll
        for (int nt = 0; nt < 2; ++nt)
#pragma unroll
            for (int rr = 0; rr < 4; ++rr) {
                float x = S[nt][rr] * SCALE_LOG2E_DK;
                x = fminf(fmaxf(x, -30.f), 30.f);
                float p = exp2f(x);
                lsum[rr] += p;
                Ps[(q16 * 4 + rr) * 40 + nt * 16 + l16] = f2bf(p);
            }
        // read back in A-operand layout (wave-private; same-wave DS ordering)
        bf16x8 pf = *(const bf16x8*)(Ps + l16 * 40 + q16 * 8);
        // O += P @ V from LDS (32 keys = one k-step, 32 n-tiles)
#pragma unroll
        for (int nt = 0; nt < 32; ++nt) {
            bf16x8 b = *(const bf16x8*)(VPs + (nt * 16 + l16) * 40 + q16 * 8);
            acc[nt] = __builtin_amdgcn_mfma_f32_16x16x32_bf16(pf, b, acc[nt], 0, 0, 0);
        }
    }

#pragma unroll
    for (int m = 1; m < 16; m <<= 1)
#pragma unroll
        for (int rr = 0; rr < 4; ++rr)
            lsum[rr] += __shfl_xor(lsum[rr], m, 64);

    if (l16 == 0) {
#pragma unroll
        for (int rr = 0; rr < 4; ++rr)
            l_part[g * N_ROWS + q0 + q16 * 4 + rr] = lsum[rr];
    }
    float* Ob = O_part + ((size_t)g * N_ROWS + q0) * PROJ;
#pragma unroll
    for (int nt = 0; nt < 32; ++nt)
#pragma unroll
        for (int rr = 0; rr < 4; ++rr)
            Ob[(size_t)(q16 * 4 + rr) * PROJ + nt * 16 + l16] = acc[nt][rr];
}

// ---------------------------------------------------------------- combine
__global__ void combine_kernel(const float* __restrict__ O_part,
                               const float* __restrict__ l_part,
                               float* __restrict__ out)
{
    int idx = blockIdx.x * 256 + threadIdx.x;   // 8192*128
    int row = idx >> 7;
    int c4 = (idx & 127) << 2;
    float s0 = 0, s1 = 0, s2 = 0, s3 = 0, lt = 0;
#pragma unroll
    for (int g = 0; g < GSPLIT; ++g) {
        const float* p = O_part + ((size_t)g * N_ROWS + row) * PROJ + c4;
        s0 += p[0]; s1 += p[1]; s2 += p[2]; s3 += p[3];
        lt += l_part[g * N_ROWS + row];
    }
    size_t o = (size_t)row * PROJ + c4;
    if (!(lt > 0.f)) {   // attn never launched/wrote -> finite signature 2.0
        out[o + 0] = 2.0f; out[o + 1] = 2.0f; out[o + 2] = 2.0f; out[o + 3] = 2.0f;
        return;
    }
    float inv = 1.0f / lt;
    out[o + 0] = s0 * inv;
    out[o + 1] = s1 * inv;
    out[o + 2] = s2 * inv;
    out[o + 3] = s3 * inv;
}

// ---------------------------------------------------------------- launch
extern "C" void kernel_launch(void* const* d_in, const int* in_sizes, int n_in,
                              void* d_out, int out_size, void* d_ws, size_t ws_size,
                              hipStream_t stream)
{
    (void)in_sizes; (void)n_in; (void)out_size;
    if (ws_size < ((size_t)101 << 20)) return;   // visible-fail guard

    const float* q  = (const float*)d_in[0];
    const float* k  = (const float*)d_in[1];
    const float* v  = (const float*)d_in[2];
    const float* Wq = (const float*)d_in[3];
    const float* bq = (const float*)d_in[4];
    const float* Wk = (const float*)d_in[5];
    const float* bk = (const float*)d_in[6];
    const float* Wv = (const float*)d_in[7];
    const float* bv = (const float*)d_in[8];

    char* ws = (char*)d_ws;
    u16* qp  = (u16*)(ws);                         // 8 MB
    u16* kp  = (u16*)(ws + ((size_t)8  << 20));    // 8 MB
    u16* vp  = (u16*)(ws + ((size_t)16 << 20));    // 8 MB
    u16* vpT = (u16*)(ws + ((size_t)24 << 20));    // 8 MB
    u16* WqT = (u16*)(ws + ((size_t)32 << 20));    // 1 MB each (bf16 512x1024)
    u16* WkT = (u16*)(ws + ((size_t)33 << 20));
    u16* WvT = (u16*)(ws + ((size_t)34 << 20));
    float* O_part = (float*)(ws + ((size_t)36 << 20));   // 64 MB
    float* l_part = (float*)(ws + ((size_t)100 << 20));  // 128 KB

    dim3 tb(32, 32);
    transpose_w_kernel<<<dim3(16, 32), tb, 0, stream>>>(Wq, WqT, 1024, 512);
    transpose_w_kernel<<<dim3(16, 32), tb, 0, stream>>>(Wk, WkT, 1024, 512);
    transpose_w_kernel<<<dim3(16, 32), tb, 0, stream>>>(Wv, WvT, 1024, 512);

    proj_kernel<<<dim3(64, 4, 3), 256, 0, stream>>>(q, k, v, WqT, WkT, WvT,
                                                    bq, bk, bv, qp, kp, vp);

    transpose_kernel<<<dim3(16, 256), tb, 0, stream>>>(vp, vpT, 8192, 512);

    attn_kernel<<<dim3(128, GSPLIT), 256, 0, stream>>>(qp, kp, vpT, O_part, l_part);

    combine_kernel<<<4096, 256, 0, stream>>>(O_part, l_part, (float*)d_out);
}

// Round 6
// 917.130 us; speedup vs baseline: 1.0539x; 1.0028x over previous
//
#include <hip/hip_runtime.h>
#include <hip/hip_bf16.h>
#include <stdint.h>
#include <stddef.h>

typedef unsigned short u16;
typedef short bf16x8 __attribute__((ext_vector_type(8)));   // 8 bf16 = 4 VGPRs
typedef short bf16x4 __attribute__((ext_vector_type(4)));   // 4 bf16 = 2 VGPRs
typedef float floatx4 __attribute__((ext_vector_type(4)));

#define N_ROWS 8192
#define D_MODEL 1024
#define PROJ 512
#define GSPLIT 8
#define KEYS_PER_G (N_ROWS / GSPLIT)   // 1024
#define CHUNKS (KEYS_PER_G / 32)       // 32
// exp(S/64) = 2^(S * log2(e)/64)
#define SCALE_LOG2E_DK 0.022542110013890054f

__device__ __forceinline__ float bf2f(u16 u) {
    union { unsigned int i; float f; } x; x.i = ((unsigned int)u) << 16; return x.f;
}
__device__ __forceinline__ u16 f2bf(float f) {
    __hip_bfloat16 h = __float2bfloat16(f);   // RNE
    return *reinterpret_cast<u16*>(&h);
}

// ------------------------------------------------- W transpose fp32 -> bf16
__global__ void transpose_w_kernel(const float* __restrict__ in, u16* __restrict__ out,
                                   int R, int C) {
    __shared__ u16 tile[32][33];
    int r = blockIdx.y * 32 + threadIdx.y;
    int c = blockIdx.x * 32 + threadIdx.x;
    tile[threadIdx.y][threadIdx.x] = f2bf(in[(size_t)r * C + c]);
    __syncthreads();
    int ro = blockIdx.x * 32 + threadIdx.y;
    int co = blockIdx.y * 32 + threadIdx.x;
    out[(size_t)ro * R + co] = tile[threadIdx.x][threadIdx.y];
}

// ------------------------------------------------- bf16 transpose (vp->vpT)
__global__ void transpose_kernel(const u16* __restrict__ in, u16* __restrict__ out,
                                 int R, int C) {
    __shared__ u16 tile[32][33];
    int r = blockIdx.y * 32 + threadIdx.y;
    int c = blockIdx.x * 32 + threadIdx.x;
    tile[threadIdx.y][threadIdx.x] = in[(size_t)r * C + c];
    __syncthreads();
    int ro = blockIdx.x * 32 + threadIdx.y;
    int co = blockIdx.y * 32 + threadIdx.x;
    out[(size_t)ro * R + co] = tile[threadIdx.x][threadIdx.y];
}

// ---------------------------------------------------------------- projections
// C_bf16[8192,512] = A_f32[8192,1024] @ W[1024,512] + b, via WT_bf16[512,1024].
// 128x128 tile, BK=32, 4 waves each 64x64 (4x4 of 16x16x32 MFMA).
__global__ __launch_bounds__(256) void proj_kernel(
    const float* __restrict__ qin, const float* __restrict__ kin, const float* __restrict__ vin,
    const u16* __restrict__ WqT, const u16* __restrict__ WkT, const u16* __restrict__ WvT,
    const float* __restrict__ bq, const float* __restrict__ bk, const float* __restrict__ bv,
    u16* __restrict__ qp, u16* __restrict__ kp, u16* __restrict__ vp)
{
    const int z = blockIdx.z;
    const float* A    = (z == 0) ? qin : (z == 1) ? kin : vin;
    const u16* WT     = (z == 0) ? WqT : (z == 1) ? WkT : WvT;
    const float* bias = (z == 0) ? bq  : (z == 1) ? bk  : bv;
    u16* C            = (z == 0) ? qp  : (z == 1) ? kp  : vp;

    const int m0 = blockIdx.x * 128;
    const int n0 = blockIdx.y * 128;
    __shared__ __align__(16) u16 smem[2 * 128 * 40];   // 20,480 B
    u16* As = smem;                // [128 rows][32 + 8 pad] bf16
    u16* Bs = smem + 128 * 40;

    const int t = threadIdx.x;
    const int w = t >> 6, l = t & 63;
    const int q16 = l >> 4, l16 = l & 15;
    const int wm = (w & 1) * 64, wn = (w >> 1) * 64;

    floatx4 acc[4][4] = {};

    for (int k0 = 0; k0 < D_MODEL; k0 += 32) {
        __syncthreads();
#pragma unroll
        for (int i = 0; i < 4; ++i) {
            int id = i * 256 + t;
            int r = id >> 3, c = id & 7;
            float4 f = *(const float4*)(A + (size_t)(m0 + r) * D_MODEL + k0 + c * 4);
            bf16x4 hv;
            hv[0] = (short)f2bf(f.x); hv[1] = (short)f2bf(f.y);
            hv[2] = (short)f2bf(f.z); hv[3] = (short)f2bf(f.w);
            *(bf16x4*)(As + r * 40 + c * 4) = hv;
        }
#pragma unroll
        for (int i = 0; i < 2; ++i) {
            int id = i * 256 + t;
            int r = id >> 2, c = id & 3;
            *(bf16x8*)(Bs + r * 40 + c * 8) =
                *(const bf16x8*)(WT + (size_t)(n0 + r) * D_MODEL + k0 + c * 8);
        }
        __syncthreads();

        bf16x8 af[4], bfr[4];
#pragma unroll
        for (int mi = 0; mi < 4; ++mi)
            af[mi] = *(const bf16x8*)(As + (wm + mi * 16 + l16) * 40 + q16 * 8);
#pragma unroll
        for (int ni = 0; ni < 4; ++ni)
            bfr[ni] = *(const bf16x8*)(Bs + (wn + ni * 16 + l16) * 40 + q16 * 8);
#pragma unroll
        for (int mi = 0; mi < 4; ++mi)
#pragma unroll
            for (int ni = 0; ni < 4; ++ni)
                acc[mi][ni] = __builtin_amdgcn_mfma_f32_16x16x32_bf16(
                    af[mi], bfr[ni], acc[mi][ni], 0, 0, 0);
    }

#pragma unroll
    for (int ni = 0; ni < 4; ++ni) {
        int col = n0 + wn + ni * 16 + l16;
        float bv_ = bias[col];
#pragma unroll
        for (int mi = 0; mi < 4; ++mi)
#pragma unroll
            for (int rr = 0; rr < 4; ++rr) {
                int row = m0 + wm + mi * 16 + q16 * 4 + rr;   // C/D layout (m89/m91)
                C[(size_t)row * PROJ + col] = f2bf(acc[mi][ni][rr] + bv_);
            }
    }
}

// ---------------------------------------------------------------- attention
// Flash-lite. Block: 64 Q-rows, 4 waves x 16 rows. Split-K (GSPLIT=8), BN=32.
// Round-6: occupancy fix. R5 was 1 block/CU (79KB LDS) = 1 wave/SIMD = zero
// latency hiding (Occupancy 11.9%, MfmaUtil 7.5%). Now: KP B-frags straight
// from global (L2-served, XCD-localized via g = bid&7); VPs swizzled unpadded.
// LDS: 32,768 + 5,120 = 37,888 B -> 4 blocks/CU. Grid 1024 = 4/CU.
__global__ __launch_bounds__(256) void attn_kernel(
    const u16* __restrict__ qp, const u16* __restrict__ kp, const u16* __restrict__ vpT,
    u16* __restrict__ O_part, float* __restrict__ l_part)
{
    const int t = threadIdx.x;
    const int w = t >> 6, l = t & 63;
    const int q16 = l >> 4, l16 = l & 15;
    const int bid = blockIdx.x;
    const int g = bid & 7;          // same-g blocks -> same XCD (rr dispatch)
    const int qt = bid >> 3;
    const int q0 = qt * 64 + w * 16;

    __shared__ __align__(16) u16 VPs[512 * 32];    // [512 n][32 k] XOR-swizzled, 32,768 B
    __shared__ __align__(16) u16 PsA[4 * 16 * 40]; // per-wave P 16x(32+8), 5,120 B
    u16* Ps = PsA + w * 640;

    bf16x8 qf[16];
#pragma unroll
    for (int s = 0; s < 16; ++s)
        qf[s] = *(const bf16x8*)(qp + (size_t)(q0 + l16) * PROJ + s * 32 + q16 * 8);

    floatx4 acc[32] = {};
    float lsum[4] = {0.f, 0.f, 0.f, 0.f};
    const int kbase = g * KEYS_PER_G;

    for (int ci = 0; ci < CHUNKS; ++ci) {
        const int k0 = kbase + ci * 32;
        __syncthreads();   // protect VPs from previous chunk's PV reads
        // stage VP chunk: 512 rows x 4 chunks(16B), slot = c ^ s(n), s(n)=(n+(n>>2))&3
#pragma unroll
        for (int i = 0; i < 8; ++i) {
            int id = i * 256 + t;
            int n = id >> 2, c = id & 3;
            int sw = (n + (n >> 2)) & 3;
            *(bf16x8*)(VPs + n * 32 + ((c ^ sw) * 8)) =
                *(const bf16x8*)(vpT + (size_t)n * N_ROWS + k0 + c * 8);
        }
        __syncthreads();

        // S[16x32] = qp_tile @ kp_chunk^T ; B-frags direct from global kp
        floatx4 S[2] = {};
#pragma unroll
        for (int nt = 0; nt < 2; ++nt) {
            const u16* krow = kp + (size_t)(k0 + nt * 16 + l16) * PROJ + q16 * 8;
#pragma unroll
            for (int s = 0; s < 16; ++s) {
                bf16x8 b = *(const bf16x8*)(krow + s * 32);
                S[nt] = __builtin_amdgcn_mfma_f32_16x16x32_bf16(qf[s], b, S[nt], 0, 0, 0);
            }
        }
        // P = exp2(clamp(S*c)); row-sum partials; C-layout -> LDS
#pragma unroll
        for (int nt = 0; nt < 2; ++nt)
#pragma unroll
            for (int rr = 0; rr < 4; ++rr) {
                float x = S[nt][rr] * SCALE_LOG2E_DK;
                x = fminf(fmaxf(x, -30.f), 30.f);
                float p = exp2f(x);
                lsum[rr] += p;
                Ps[(q16 * 4 + rr) * 40 + nt * 16 + l16] = f2bf(p);
            }
        // read back in A-operand layout (wave-private; same-wave DS ordering)
        bf16x8 pf = *(const bf16x8*)(Ps + l16 * 40 + q16 * 8);
        // O += P @ V from swizzled VPs
#pragma unroll
        for (int nt = 0; nt < 32; ++nt) {
            int n = nt * 16 + l16;
            int sw = (n + (n >> 2)) & 3;
            bf16x8 b = *(const bf16x8*)(VPs + n * 32 + ((q16 ^ sw) * 8));
            acc[nt] = __builtin_amdgcn_mfma_f32_16x16x32_bf16(pf, b, acc[nt], 0, 0, 0);
        }
    }

#pragma unroll
    for (int m = 1; m < 16; m <<= 1)
#pragma unroll
        for (int rr = 0; rr < 4; ++rr)
            lsum[rr] += __shfl_xor(lsum[rr], m, 64);

    if (l16 == 0) {
#pragma unroll
        for (int rr = 0; rr < 4; ++rr)
            l_part[g * N_ROWS + q0 + q16 * 4 + rr] = lsum[rr];
    }
    u16* Ob = O_part + ((size_t)g * N_ROWS + q0) * PROJ;
#pragma unroll
    for (int nt = 0; nt < 32; ++nt)
#pragma unroll
        for (int rr = 0; rr < 4; ++rr)
            Ob[(size_t)(q16 * 4 + rr) * PROJ + nt * 16 + l16] = f2bf(acc[nt][rr]);
}

// ---------------------------------------------------------------- combine
__global__ void combine_kernel(const u16* __restrict__ O_part,
                               const float* __restrict__ l_part,
                               float* __restrict__ out)
{
    int idx = blockIdx.x * 256 + threadIdx.x;   // 8192*128
    int row = idx >> 7;
    int c4 = (idx & 127) << 2;
    float s0 = 0, s1 = 0, s2 = 0, s3 = 0, lt = 0;
#pragma unroll
    for (int g = 0; g < GSPLIT; ++g) {
        const u16* p = O_part + ((size_t)g * N_ROWS + row) * PROJ + c4;
        s0 += bf2f(p[0]); s1 += bf2f(p[1]); s2 += bf2f(p[2]); s3 += bf2f(p[3]);
        lt += l_part[g * N_ROWS + row];
    }
    size_t o = (size_t)row * PROJ + c4;
    if (!(lt > 0.f)) {   // attn never launched/wrote -> finite signature 2.0
        out[o + 0] = 2.0f; out[o + 1] = 2.0f; out[o + 2] = 2.0f; out[o + 3] = 2.0f;
        return;
    }
    float inv = 1.0f / lt;
    out[o + 0] = s0 * inv;
    out[o + 1] = s1 * inv;
    out[o + 2] = s2 * inv;
    out[o + 3] = s3 * inv;
}

// ---------------------------------------------------------------- launch
extern "C" void kernel_launch(void* const* d_in, const int* in_sizes, int n_in,
                              void* d_out, int out_size, void* d_ws, size_t ws_size,
                              hipStream_t stream)
{
    (void)in_sizes; (void)n_in; (void)out_size;
    if (ws_size < ((size_t)101 << 20)) return;   // visible-fail guard

    const float* q  = (const float*)d_in[0];
    const float* k  = (const float*)d_in[1];
    const float* v  = (const float*)d_in[2];
    const float* Wq = (const float*)d_in[3];
    const float* bq = (const float*)d_in[4];
    const float* Wk = (const float*)d_in[5];
    const float* bk = (const float*)d_in[6];
    const float* Wv = (const float*)d_in[7];
    const float* bv = (const float*)d_in[8];

    char* ws = (char*)d_ws;
    u16* qp  = (u16*)(ws);                         // 8 MB
    u16* kp  = (u16*)(ws + ((size_t)8  << 20));    // 8 MB
    u16* vp  = (u16*)(ws + ((size_t)16 << 20));    // 8 MB
    u16* vpT = (u16*)(ws + ((size_t)24 << 20));    // 8 MB
    u16* WqT = (u16*)(ws + ((size_t)32 << 20));    // 1 MB each (bf16 512x1024)
    u16* WkT = (u16*)(ws + ((size_t)33 << 20));
    u16* WvT = (u16*)(ws + ((size_t)34 << 20));
    u16* O_part   = (u16*)(ws + ((size_t)36 << 20));     // bf16[8][8192][512] = 64 MB
    float* l_part = (float*)(ws + ((size_t)100 << 20));  // fp32[8][8192] = 256 KB

    dim3 tb(32, 32);
    transpose_w_kernel<<<dim3(16, 32), tb, 0, stream>>>(Wq, WqT, 1024, 512);
    transpose_w_kernel<<<dim3(16, 32), tb, 0, stream>>>(Wk, WkT, 1024, 512);
    transpose_w_kernel<<<dim3(16, 32), tb, 0, stream>>>(Wv, WvT, 1024, 512);

    proj_kernel<<<dim3(64, 4, 3), 256, 0, stream>>>(q, k, v, WqT, WkT, WvT,
                                                    bq, bk, bv, qp, kp, vp);

    transpose_kernel<<<dim3(16, 256), tb, 0, stream>>>(vp, vpT, 8192, 512);

    attn_kernel<<<dim3(128 * GSPLIT), 256, 0, stream>>>(qp, kp, vpT, O_part, l_part);

    combine_kernel<<<4096, 256, 0, stream>>>(O_part, l_part, (float*)d_out);
}

// Round 7
// 453.972 us; speedup vs baseline: 2.1290x; 2.0202x over previous
//
#include <hip/hip_runtime.h>
#include <hip/hip_bf16.h>
#include <stdint.h>
#include <stddef.h>

typedef unsigned short u16;
typedef short bf16x8 __attribute__((ext_vector_type(8)));   // 8 bf16 = 4 VGPRs
typedef short bf16x4 __attribute__((ext_vector_type(4)));   // 4 bf16 = 2 VGPRs
typedef float floatx4 __attribute__((ext_vector_type(4)));

#define N_ROWS 8192
#define D_MODEL 1024
#define PROJ 512
#define MHALF 4096          // keys per half-pass (P_half = 8192 x 4096 bf16 = 64 MB)
// exp(S/64) = 2^(S * log2(e)/64)
#define SCALE_LOG2E_DK 0.022542110013890054f

__device__ __forceinline__ float bf2f(u16 u) {
    union { unsigned int i; float f; } x; x.i = ((unsigned int)u) << 16; return x.f;
}
__device__ __forceinline__ u16 f2bf(float f) {
    __hip_bfloat16 h = __float2bfloat16(f);   // RNE
    return *reinterpret_cast<u16*>(&h);
}

// ------------------------------------------------- W transpose fp32 -> bf16
__global__ void transpose_w_kernel(const float* __restrict__ in, u16* __restrict__ out,
                                   int R, int C) {
    __shared__ u16 tile[32][33];
    int r = blockIdx.y * 32 + threadIdx.y;
    int c = blockIdx.x * 32 + threadIdx.x;
    tile[threadIdx.y][threadIdx.x] = f2bf(in[(size_t)r * C + c]);
    __syncthreads();
    int ro = blockIdx.x * 32 + threadIdx.y;
    int co = blockIdx.y * 32 + threadIdx.x;
    out[(size_t)ro * R + co] = tile[threadIdx.x][threadIdx.y];
}

// ------------------------------------------------- bf16 transpose (vp->vpT)
__global__ void transpose_kernel(const u16* __restrict__ in, u16* __restrict__ out,
                                 int R, int C) {
    __shared__ u16 tile[32][33];
    int r = blockIdx.y * 32 + threadIdx.y;
    int c = blockIdx.x * 32 + threadIdx.x;
    tile[threadIdx.y][threadIdx.x] = in[(size_t)r * C + c];
    __syncthreads();
    int ro = blockIdx.x * 32 + threadIdx.y;
    int co = blockIdx.y * 32 + threadIdx.x;
    out[(size_t)ro * R + co] = tile[threadIdx.x][threadIdx.y];
}

// ---------------------------------------------------------------- projections
// C_bf16[8192,512] = A_f32[8192,1024] @ W[1024,512] + b, via WT_bf16[512,1024].
// 128x128 tile, BK=32, 4 waves each 64x64 (4x4 of 16x16x32 MFMA).
__global__ __launch_bounds__(256) void proj_kernel(
    const float* __restrict__ qin, const float* __restrict__ kin, const float* __restrict__ vin,
    const u16* __restrict__ WqT, const u16* __restrict__ WkT, const u16* __restrict__ WvT,
    const float* __restrict__ bq, const float* __restrict__ bk, const float* __restrict__ bv,
    u16* __restrict__ qp, u16* __restrict__ kp, u16* __restrict__ vp)
{
    const int z = blockIdx.z;
    const float* A    = (z == 0) ? qin : (z == 1) ? kin : vin;
    const u16* WT     = (z == 0) ? WqT : (z == 1) ? WkT : WvT;
    const float* bias = (z == 0) ? bq  : (z == 1) ? bk  : bv;
    u16* C            = (z == 0) ? qp  : (z == 1) ? kp  : vp;

    const int m0 = blockIdx.x * 128;
    const int n0 = blockIdx.y * 128;
    __shared__ __align__(16) u16 smem[2 * 128 * 40];   // 20,480 B
    u16* As = smem;                // [128 rows][32 + 8 pad] bf16
    u16* Bs = smem + 128 * 40;

    const int t = threadIdx.x;
    const int w = t >> 6, l = t & 63;
    const int q16 = l >> 4, l16 = l & 15;
    const int wm = (w & 1) * 64, wn = (w >> 1) * 64;

    floatx4 acc[4][4] = {};

    for (int k0 = 0; k0 < D_MODEL; k0 += 32) {
        __syncthreads();
#pragma unroll
        for (int i = 0; i < 4; ++i) {
            int id = i * 256 + t;
            int r = id >> 3, c = id & 7;
            float4 f = *(const float4*)(A + (size_t)(m0 + r) * D_MODEL + k0 + c * 4);
            bf16x4 hv;
            hv[0] = (short)f2bf(f.x); hv[1] = (short)f2bf(f.y);
            hv[2] = (short)f2bf(f.z); hv[3] = (short)f2bf(f.w);
            *(bf16x4*)(As + r * 40 + c * 4) = hv;
        }
#pragma unroll
        for (int i = 0; i < 2; ++i) {
            int id = i * 256 + t;
            int r = id >> 2, c = id & 3;
            *(bf16x8*)(Bs + r * 40 + c * 8) =
                *(const bf16x8*)(WT + (size_t)(n0 + r) * D_MODEL + k0 + c * 8);
        }
        __syncthreads();

        bf16x8 af[4], bfr[4];
#pragma unroll
        for (int mi = 0; mi < 4; ++mi)
            af[mi] = *(const bf16x8*)(As + (wm + mi * 16 + l16) * 40 + q16 * 8);
#pragma unroll
        for (int ni = 0; ni < 4; ++ni)
            bfr[ni] = *(const bf16x8*)(Bs + (wn + ni * 16 + l16) * 40 + q16 * 8);
#pragma unroll
        for (int mi = 0; mi < 4; ++mi)
#pragma unroll
            for (int ni = 0; ni < 4; ++ni)
                acc[mi][ni] = __builtin_amdgcn_mfma_f32_16x16x32_bf16(
                    af[mi], bfr[ni], acc[mi][ni], 0, 0, 0);
    }

#pragma unroll
    for (int ni = 0; ni < 4; ++ni) {
        int col = n0 + wn + ni * 16 + l16;
        float bv_ = bias[col];
#pragma unroll
        for (int mi = 0; mi < 4; ++mi)
#pragma unroll
            for (int rr = 0; rr < 4; ++rr) {
                int row = m0 + wm + mi * 16 + q16 * 4 + rr;   // C/D layout (m89/m91)
                C[(size_t)row * PROJ + col] = f2bf(acc[mi][ni][rr] + bv_);
            }
    }
}

// ---------------------------------------------------------------- zero l
__global__ void zero_l_kernel(float* __restrict__ l) {
    l[blockIdx.x * 256 + threadIdx.x] = 0.f;
}

// ---------------------------------------------------------------- score pass
// P[8192][4096] = exp2(c * (qp @ kp_h^T)) bf16, l[row] += rowsums (atomic).
// m97 skeleton: 128x128 tile, K=512 (16 chunks), grid 64x32 = 2048 blocks.
__global__ __launch_bounds__(256) void score_kernel(
    const u16* __restrict__ qp, const u16* __restrict__ kph,
    u16* __restrict__ P, float* __restrict__ l)
{
    const int m0 = blockIdx.x * 128;
    const int n0 = blockIdx.y * 128;
    __shared__ __align__(16) u16 smem[2 * 128 * 40];   // 20,480 B
    u16* As = smem;
    u16* Bs = smem + 128 * 40;

    const int t = threadIdx.x;
    const int w = t >> 6, lane = t & 63;
    const int q16 = lane >> 4, l16 = lane & 15;
    const int wm = (w & 1) * 64, wn = (w >> 1) * 64;

    floatx4 acc[4][4] = {};

    for (int k0 = 0; k0 < PROJ; k0 += 32) {
        __syncthreads();
#pragma unroll
        for (int i = 0; i < 2; ++i) {
            int id = i * 256 + t;
            int r = id >> 2, c = id & 3;
            *(bf16x8*)(As + r * 40 + c * 8) =
                *(const bf16x8*)(qp + (size_t)(m0 + r) * PROJ + k0 + c * 8);
            *(bf16x8*)(Bs + r * 40 + c * 8) =
                *(const bf16x8*)(kph + (size_t)(n0 + r) * PROJ + k0 + c * 8);
        }
        __syncthreads();

        bf16x8 af[4], bfr[4];
#pragma unroll
        for (int mi = 0; mi < 4; ++mi)
            af[mi] = *(const bf16x8*)(As + (wm + mi * 16 + l16) * 40 + q16 * 8);
#pragma unroll
        for (int ni = 0; ni < 4; ++ni)
            bfr[ni] = *(const bf16x8*)(Bs + (wn + ni * 16 + l16) * 40 + q16 * 8);
#pragma unroll
        for (int mi = 0; mi < 4; ++mi)
#pragma unroll
            for (int ni = 0; ni < 4; ++ni)
                acc[mi][ni] = __builtin_amdgcn_mfma_f32_16x16x32_bf16(
                    af[mi], bfr[ni], acc[mi][ni], 0, 0, 0);
    }

    // epilogue: exp2, store P, fused row-sums -> atomicAdd l
#pragma unroll
    for (int mi = 0; mi < 4; ++mi)
#pragma unroll
        for (int rr = 0; rr < 4; ++rr) {
            int row = m0 + wm + mi * 16 + q16 * 4 + rr;
            u16* Prow = P + (size_t)row * MHALF + n0 + wn;
            float tot = 0.f;
#pragma unroll
            for (int ni = 0; ni < 4; ++ni) {
                float x = acc[mi][ni][rr] * SCALE_LOG2E_DK;
                x = fminf(fmaxf(x, -30.f), 30.f);
                float p = exp2f(x);
                tot += p;
                Prow[ni * 16 + l16] = f2bf(p);
            }
#pragma unroll
            for (int m = 1; m < 16; m <<= 1)
                tot += __shfl_xor(tot, m, 64);
            if (l16 == 0)
                atomicAdd(&l[row], tot);
        }
}

// ---------------------------------------------------------------- PV pass
// O += P[8192][4096] @ V_h.  B^T = vpT rows (pre-offset by h*4096 in k).
// Grid (64 m, 4 n, 2 kg); kg0 -> Ofull fp32, kg1 -> Opart bf16; accum flag.
__global__ __launch_bounds__(256) void pv_kernel(
    const u16* __restrict__ P, const u16* __restrict__ vpTh,
    float* __restrict__ Ofull, u16* __restrict__ Opart, int accum)
{
    const int m0 = blockIdx.x * 128;
    const int n0 = blockIdx.y * 128;
    const int kg = blockIdx.z;
    const int kbase = kg * 2048;
    __shared__ __align__(16) u16 smem[2 * 128 * 40];   // 20,480 B
    u16* As = smem;
    u16* Bs = smem + 128 * 40;

    const int t = threadIdx.x;
    const int w = t >> 6, lane = t & 63;
    const int q16 = lane >> 4, l16 = lane & 15;
    const int wm = (w & 1) * 64, wn = (w >> 1) * 64;

    floatx4 acc[4][4] = {};

    for (int kk = 0; kk < 2048; kk += 32) {
        const int k0 = kbase + kk;
        __syncthreads();
#pragma unroll
        for (int i = 0; i < 2; ++i) {
            int id = i * 256 + t;
            int r = id >> 2, c = id & 3;
            *(bf16x8*)(As + r * 40 + c * 8) =
                *(const bf16x8*)(P + (size_t)(m0 + r) * MHALF + k0 + c * 8);
            *(bf16x8*)(Bs + r * 40 + c * 8) =
                *(const bf16x8*)(vpTh + (size_t)(n0 + r) * N_ROWS + k0 + c * 8);
        }
        __syncthreads();

        bf16x8 af[4], bfr[4];
#pragma unroll
        for (int mi = 0; mi < 4; ++mi)
            af[mi] = *(const bf16x8*)(As + (wm + mi * 16 + l16) * 40 + q16 * 8);
#pragma unroll
        for (int ni = 0; ni < 4; ++ni)
            bfr[ni] = *(const bf16x8*)(Bs + (wn + ni * 16 + l16) * 40 + q16 * 8);
#pragma unroll
        for (int mi = 0; mi < 4; ++mi)
#pragma unroll
            for (int ni = 0; ni < 4; ++ni)
                acc[mi][ni] = __builtin_amdgcn_mfma_f32_16x16x32_bf16(
                    af[mi], bfr[ni], acc[mi][ni], 0, 0, 0);
    }

#pragma unroll
    for (int ni = 0; ni < 4; ++ni) {
        int col = n0 + wn + ni * 16 + l16;
#pragma unroll
        for (int mi = 0; mi < 4; ++mi)
#pragma unroll
            for (int rr = 0; rr < 4; ++rr) {
                int row = m0 + wm + mi * 16 + q16 * 4 + rr;
                size_t o = (size_t)row * PROJ + col;
                float v = acc[mi][ni][rr];
                if (kg == 0) {
                    if (accum) v += Ofull[o];
                    Ofull[o] = v;
                } else {
                    if (accum) v += bf2f(Opart[o]);
                    Opart[o] = f2bf(v);
                }
            }
    }
}

// ---------------------------------------------------------------- scale
__global__ void scale_kernel(float* __restrict__ out, const u16* __restrict__ Opart,
                             const float* __restrict__ l)
{
    int idx = blockIdx.x * 256 + threadIdx.x;   // 8192*512
    int row = idx >> 9;
    out[idx] = (out[idx] + bf2f(Opart[idx])) / l[row];
}

// ---------------------------------------------------------------- launch
extern "C" void kernel_launch(void* const* d_in, const int* in_sizes, int n_in,
                              void* d_out, int out_size, void* d_ws, size_t ws_size,
                              hipStream_t stream)
{
    (void)in_sizes; (void)n_in; (void)out_size;
    if (ws_size < ((size_t)101 << 20)) return;   // visible-fail guard

    const float* q  = (const float*)d_in[0];
    const float* k  = (const float*)d_in[1];
    const float* v  = (const float*)d_in[2];
    const float* Wq = (const float*)d_in[3];
    const float* bq = (const float*)d_in[4];
    const float* Wk = (const float*)d_in[5];
    const float* bk = (const float*)d_in[6];
    const float* Wv = (const float*)d_in[7];
    const float* bv = (const float*)d_in[8];

    char* ws = (char*)d_ws;
    u16* qp    = (u16*)(ws);                        // 8 MB
    u16* kp    = (u16*)(ws + ((size_t)8  << 20));   // 8 MB
    u16* vp    = (u16*)(ws + ((size_t)16 << 20));   // 8 MB (dead after vpT -> reused as Opart)
    u16* vpT   = (u16*)(ws + ((size_t)24 << 20));   // 8 MB
    u16* WqT   = (u16*)(ws + ((size_t)32 << 20));   // 1 MB each (bf16 512x1024)
    u16* WkT   = (u16*)(ws + ((size_t)33 << 20));
    u16* WvT   = (u16*)(ws + ((size_t)34 << 20));
    float* l   = (float*)(ws + ((size_t)35 << 20)); // 32 KB
    u16* P     = (u16*)(ws + ((size_t)36 << 20));   // 64 MB (half-P, reused per half)
    u16* Opart = vp;                                // kg1 partial, bf16 8 MB
    float* Ofull = (float*)d_out;                   // kg0 partial accumulates in d_out

    dim3 tb(32, 32);
    transpose_w_kernel<<<dim3(16, 32), tb, 0, stream>>>(Wq, WqT, 1024, 512);
    transpose_w_kernel<<<dim3(16, 32), tb, 0, stream>>>(Wk, WkT, 1024, 512);
    transpose_w_kernel<<<dim3(16, 32), tb, 0, stream>>>(Wv, WvT, 1024, 512);

    proj_kernel<<<dim3(64, 4, 3), 256, 0, stream>>>(q, k, v, WqT, WkT, WvT,
                                                    bq, bk, bv, qp, kp, vp);

    transpose_kernel<<<dim3(16, 256), tb, 0, stream>>>(vp, vpT, 8192, 512);

    zero_l_kernel<<<32, 256, 0, stream>>>(l);

    // half 0
    score_kernel<<<dim3(64, 32), 256, 0, stream>>>(qp, kp, P, l);
    pv_kernel<<<dim3(64, 4, 2), 256, 0, stream>>>(P, vpT, Ofull, Opart, 0);
    // half 1
    score_kernel<<<dim3(64, 32), 256, 0, stream>>>(qp, kp + (size_t)MHALF * PROJ, P, l);
    pv_kernel<<<dim3(64, 4, 2), 256, 0, stream>>>(P, vpT + MHALF, Ofull, Opart, 1);

    scale_kernel<<<16384, 256, 0, stream>>>(Ofull, Opart, l);
}